// Round 5
// baseline (7647.721 us; speedup 1.0000x reference)
//
#include <hip/hip_runtime.h>
#include <hip/hip_fp16.h>

// LayerNormLSTMCell: B=128, T=512, D=512, U=512, 4 gates (f,g,i,o), shared LN.
// Numerics: split-bf16 (hi+lo) on both operands of every GEMM, 3-product MFMA
// (hi*hi + lo*hi + hi*lo) ~= fp32; xz stored fp16. PASSED r3 at absmax 0.0039.
//
// Exchange protocol (R8/R9, verified): value-only payload (acts f32, z-stats
// packed (S,Q) u64) via relaxed agent-scope stores (write-through LLC),
// ordered by one tagged FLAG per producer WG:
//   producer: payload stores -> s_waitcnt vmcnt(0) -> __syncthreads -> flag
//   consumer: 1 thread/producer spins flag -> __syncthreads -> coalesced loads
// Parity double-buffer overwrite safety: producer's t+2 write ordered after
// every consumer's t read via the all-flags phase-3 gate.
//
// R10: occupancy doubling. R9 counters: Occupancy 11.8% = 1 WG/CU (grid 256),
// MfmaUtil 6%, VALU 18%, HBM 2.6% -- every pipe idle; the ~20K cy/step of
// LLC sync latency is unhidden because the CU has nothing else to run.
// Now: 512 WGs = 2/CU, co-resident pair from DIFFERENT clusters (cid=bid>>5
// -> bid and bid+256 differ in cid) so one cluster computes while the other
// waits. To fit 2 WGs/CU at <=256 VGPR: WPC 16->32 (64 units/WG) halves the
// VGPR-resident weights to 128 VGPR. BPC stays 8. launch_bounds(256,2).
// LDS 37.9KB x2 = 75.8KB < 160KB. All 512 WGs co-resident (512 slots exactly).

typedef unsigned short ushort_t;
typedef unsigned long long u64;
typedef __attribute__((ext_vector_type(8))) short short8;
typedef __attribute__((ext_vector_type(4))) float f32x4;

#define Bsz 128
#define Tn  512
#define Un  512
#define NU  2048
#define NC  16     // clusters
#define WPC 32     // WGs per cluster (each owns 64 units of one gate)
#define BPC 8      // batches per cluster

#define GIDX(u) ((u) + ((u) >> 5))   // LDS skew for gamma/beta

__device__ __forceinline__ ushort_t f2bf(float f){
  unsigned u = __float_as_uint(f);
  u = u + 0x7fffu + ((u >> 16) & 1u);   // RNE
  return (ushort_t)(u >> 16);
}
__device__ __forceinline__ float bf2f(ushort_t h){
  return __uint_as_float(((unsigned)h) << 16);
}
__device__ __forceinline__ float sigf(float x){ return 1.0f/(1.0f + __expf(-x)); }
__device__ __forceinline__ float tanh_fast(float x){
  float ax = fabsf(x);
  float e  = __expf(-2.0f*ax);          // in (0,1], no overflow
  float r  = (1.0f - e)/(1.0f + e);
  return x >= 0.0f ? r : -r;
}

// ---- LLC-direct primitives (relaxed agent scope) ----
__device__ __forceinline__ void st_tag(u64* p, float v, unsigned tag){
  u64 w = ((u64)tag << 32) | (u64)__float_as_uint(v);
  __hip_atomic_store(p, w, __ATOMIC_RELAXED, __HIP_MEMORY_SCOPE_AGENT);
}
__device__ __forceinline__ void st_u64(u64* p, u64 w){
  __hip_atomic_store(p, w, __ATOMIC_RELAXED, __HIP_MEMORY_SCOPE_AGENT);
}
__device__ __forceinline__ void st_f32(float* p, float v){
  __hip_atomic_store(p, v, __ATOMIC_RELAXED, __HIP_MEMORY_SCOPE_AGENT);
}
__device__ __forceinline__ u64 ld_u64(const u64* p){
  return __hip_atomic_load(p, __ATOMIC_RELAXED, __HIP_MEMORY_SCOPE_AGENT);
}
__device__ __forceinline__ float lo_f(u64 w){ return __uint_as_float((unsigned)w); }
__device__ __forceinline__ float hi_f(u64 w){ return __uint_as_float((unsigned)(w >> 32)); }

// ---------------- weight prep: Wh -> fragment-ordered hi/lo ----------------
// layout: idx = (((wid*4 + wave)*16 + ki)*64 + lane)*8 + j
//   wid 0..31 (64 units of gate wid>>3), wave 0..3 (16 units), ki 0..15
//   u = (wid&7)*64 + wave*16 + (lane&15); k = ki*32 + (lane>>4)*8 + j
__global__ void k_prep_w(const float* __restrict__ Wf, const float* __restrict__ Wg,
                         const float* __restrict__ Wi, const float* __restrict__ Wo,
                         ushort_t* __restrict__ wh_hi, ushort_t* __restrict__ wh_lo){
  int idx = blockIdx.x*blockDim.x + threadIdx.x;
  if (idx >= 1048576) return;
  const float* Wp[4] = {Wf, Wg, Wi, Wo};
  int j    = idx & 7;
  int lane = (idx >> 3) & 63;
  int ki   = (idx >> 9) & 15;
  int wave = (idx >> 13) & 3;
  int wid  = idx >> 15;
  int gate = wid >> 3;
  int u = (wid & 7)*64 + wave*16 + (lane & 15);
  int k = ki*32 + (lane >> 4)*8 + j;
  float w = Wp[gate][u*1024 + k];
  ushort_t hi = f2bf(w);
  wh_hi[idx] = hi;
  wh_lo[idx] = f2bf(w - bf2f(hi));
}

// ---------------- xz = x @ Wx^T  (split-bf16 MFMA, 128x128 tile, BK=32) ----------------
__global__ __launch_bounds__(256,2) void k_gemm_xz(const float* __restrict__ A,
    const float* __restrict__ Wf, const float* __restrict__ Wg,
    const float* __restrict__ Wi, const float* __restrict__ Wo,
    __half* __restrict__ C){
  __shared__ __align__(16) ushort_t Ah[128*32];
  __shared__ __align__(16) ushort_t Al[128*32];
  __shared__ __align__(16) ushort_t Bh[128*32];
  __shared__ __align__(16) ushort_t Bl[128*32];
  const int tid  = threadIdx.x;
  const int lane = tid & 63, wave = tid >> 6;
  const int quad = lane >> 4, l15 = lane & 15;
  const int wm = wave >> 1, wn = wave & 1;
  const int m0 = blockIdx.x * 128, n0 = blockIdx.y * 128;
  const float* Wp = (n0 < 512) ? Wf : (n0 < 1024) ? Wg : (n0 < 1536) ? Wi : Wo;
  const int u0 = n0 & 511;
  f32x4 acc[4][4];
  #pragma unroll
  for (int a=0;a<4;a++)
    #pragma unroll
    for (int b=0;b<4;b++) acc[a][b] = (f32x4){0.f,0.f,0.f,0.f};

  for (int kc = 0; kc < 512; kc += 32){
    __syncthreads();
    #pragma unroll
    for (int p=0; p<4; p++){
      int slot = p*256 + tid;
      int row = slot >> 3, seg = slot & 7;
      float4 va = *(const float4*)(A  + (size_t)(m0+row)*512  + kc + seg*4);
      float4 vb = *(const float4*)(Wp + (size_t)(u0+row)*1024 + 512 + kc + seg*4);
      ushort4 ah, al, bh, bl;
      ah.x=f2bf(va.x); al.x=f2bf(va.x-bf2f(ah.x));
      ah.y=f2bf(va.y); al.y=f2bf(va.y-bf2f(ah.y));
      ah.z=f2bf(va.z); al.z=f2bf(va.z-bf2f(ah.z));
      ah.w=f2bf(va.w); al.w=f2bf(va.w-bf2f(ah.w));
      bh.x=f2bf(vb.x); bl.x=f2bf(vb.x-bf2f(bh.x));
      bh.y=f2bf(vb.y); bl.y=f2bf(vb.y-bf2f(bh.y));
      bh.z=f2bf(vb.z); bl.z=f2bf(vb.z-bf2f(bh.z));
      bh.w=f2bf(vb.w); bl.w=f2bf(vb.w-bf2f(bh.w));
      *(ushort4*)(Ah + slot*4) = ah;
      *(ushort4*)(Al + slot*4) = al;
      *(ushort4*)(Bh + slot*4) = bh;
      *(ushort4*)(Bl + slot*4) = bl;
    }
    __syncthreads();
    short8 afh[4], afl[4], bfh[4], bfl[4];
    #pragma unroll
    for (int ti=0; ti<4; ti++){
      afh[ti] = *(const short8*)(Ah + (wm*64 + ti*16 + l15)*32 + quad*8);
      afl[ti] = *(const short8*)(Al + (wm*64 + ti*16 + l15)*32 + quad*8);
    }
    #pragma unroll
    for (int tj=0; tj<4; tj++){
      bfh[tj] = *(const short8*)(Bh + (wn*64 + tj*16 + l15)*32 + quad*8);
      bfl[tj] = *(const short8*)(Bl + (wn*64 + tj*16 + l15)*32 + quad*8);
    }
    #pragma unroll
    for (int ti=0; ti<4; ti++)
      #pragma unroll
      for (int tj=0; tj<4; tj++){
        acc[ti][tj] = __builtin_amdgcn_mfma_f32_16x16x32_bf16(afh[ti], bfh[tj], acc[ti][tj], 0,0,0);
        acc[ti][tj] = __builtin_amdgcn_mfma_f32_16x16x32_bf16(afl[ti], bfh[tj], acc[ti][tj], 0,0,0);
        acc[ti][tj] = __builtin_amdgcn_mfma_f32_16x16x32_bf16(afh[ti], bfl[tj], acc[ti][tj], 0,0,0);
      }
  }
  #pragma unroll
  for (int ti=0; ti<4; ti++)
    #pragma unroll
    for (int tj=0; tj<4; tj++)
      #pragma unroll
      for (int r=0; r<4; r++){
        int m = m0 + wm*64 + ti*16 + quad*4 + r;
        int n = n0 + wn*64 + tj*16 + l15;
        C[(size_t)m*NU + n] = __float2half(acc[ti][tj][r]);
      }
}

// ---------------- persistent LSTM ----------------
__global__ __launch_bounds__(256,2) void k_lstm(
    const ushort_t* __restrict__ wh_hi_g, const ushort_t* __restrict__ wh_lo_g,
    const __half* __restrict__ xz,
    const float* __restrict__ bfp, const float* __restrict__ bgp,
    const float* __restrict__ bip, const float* __restrict__ bop,
    const float* __restrict__ gamma, const float* __restrict__ beta,
    const float* __restrict__ h0, const float* __restrict__ c0,
    float* __restrict__ actf, u64* __restrict__ zbuf,
    u64* __restrict__ zflag, u64* __restrict__ aflag,
    float* __restrict__ out)
{
  const int bid = blockIdx.x;
  const int cid = bid >> 5;          // cluster; co-resident (bid, bid+256) differ -> overlap
  const int wid = bid & 31;          // 0..31; owns units [wid*64, wid*64+64) of gate wid>>3
  const int tid = threadIdx.x;
  const int wave = tid >> 6, lane = tid & 63;
  const int quad = lane >> 4, l15 = lane & 15;
  const int gate = wid >> 3;

  __shared__ __align__(16) ushort_t h_hi[16][520];   // rows 8..15 stay zero (M=8 pad to 16)
  __shared__ __align__(16) ushort_t h_lo[16][520];
  __shared__ float gamma_lds[528], beta_lds[528];    // skew-indexed via GIDX
  __shared__ float wavepart[4][8][2];

  for (int i = tid; i < 16*520; i += 256){
    int r = i / 520, u = i - r*520;
    float v = (r < BPC && u < 512) ? h0[(cid*BPC + r)*512 + u] : 0.0f;
    ushort_t hh = f2bf(v);
    h_hi[r][u] = hh;
    h_lo[r][u] = f2bf(v - bf2f(hh));
  }
  for (int i = tid; i < 512; i += 256){ gamma_lds[GIDX(i)] = gamma[i]; beta_lds[GIDX(i)] = beta[i]; }

  // replicated c-state: thread owns (b_loc, 16 units interleaved)
  const int b_loc = tid >> 5;
  const int l2 = (tid & 31) << 1;
  float c[16];
  #pragma unroll
  for (int i=0;i<16;i++) c[i] = c0[(cid*BPC + b_loc)*512 + (i>>1)*64 + l2 + (i&1)];

  // VGPR-resident Wh B-fragments, hi+lo (16 units per wave -> 128 VGPR total)
  short8 wrh[16], wrl[16];
  {
    const ushort_t* wph = wh_hi_g + (size_t)(wid*4 + wave)*8192 + lane*8;
    const ushort_t* wpl = wh_lo_g + (size_t)(wid*4 + wave)*8192 + lane*8;
    #pragma unroll
    for (int i=0;i<16;i++){
      wrh[i] = *(const short8*)(wph + (size_t)i*512);
      wrl[i] = *(const short8*)(wpl + (size_t)i*512);
    }
  }

  const int ng = wid*64 + wave*16 + l15;   // this thread's unit (global gate-unit index)
  const int uu = ng & 511;
  float bias_r, gam_r, bet_r;
  {
    const float* bp = (gate==0)? bfp : (gate==1)? bgp : (gate==2)? bip : bop;
    bias_r = bp[uu];
    gam_r = gamma[uu]; bet_r = beta[uu];
  }
  const bool bvalid = (quad < 2);
  const int b_base = quad*4;

  __syncthreads();

  for (int t = 0; t < Tn; ++t){
    const unsigned tag = (unsigned)(t + 1);
    const int par = t & 1;
    const size_t fb = (size_t)(par*NC + cid)*WPC;
    // ---- phase 1: z = h @ Wh^T + xz + bias  (split-bf16, 3 products) ----
    float xzv[4];
    #pragma unroll
    for (int r=0; r<4; r++){
      if (bvalid){
        int b = cid*BPC + b_base + r;
        xzv[r] = __half2float(xz[((size_t)b*Tn + t)*NU + ng]);
      } else xzv[r] = 0.0f;
    }
    f32x4 acc = (f32x4){0.f,0.f,0.f,0.f};
    #pragma unroll
    for (int ki=0; ki<16; ki++){
      short8 afh = *(const short8*)(&h_hi[l15][ki*32 + quad*8]);
      short8 afl = *(const short8*)(&h_lo[l15][ki*32 + quad*8]);
      acc = __builtin_amdgcn_mfma_f32_16x16x32_bf16(afh, wrh[ki], acc, 0,0,0);
      acc = __builtin_amdgcn_mfma_f32_16x16x32_bf16(afl, wrh[ki], acc, 0,0,0);
      acc = __builtin_amdgcn_mfma_f32_16x16x32_bf16(afh, wrl[ki], acc, 0,0,0);
    }
    float z[4];
    #pragma unroll
    for (int r=0;r<4;r++)
      z[r] = bvalid ? (acc[r] + xzv[r] + bias_r) : 0.0f;

    // wave-local stats over its 16 units (per batch r)
    float sum[4], ssq[4];
    #pragma unroll
    for (int r=0;r<4;r++){
      float s = z[r];
      float q = z[r]*z[r];
      #pragma unroll
      for (int off=1; off<16; off<<=1){ s += __shfl_xor(s, off); q += __shfl_xor(q, off); }
      sum[r]=s; ssq[r]=q;
    }
    if (l15 == 0 && bvalid){
      #pragma unroll
      for (int r=0;r<4;r++){
        wavepart[wave][b_base + r][0] = sum[r];
        wavepart[wave][b_base + r][1] = ssq[r];
      }
    }
    __syncthreads();
    // per-WG (S,Q) partial over its 64 units, per batch, value-only packed u64
    if (tid < 8){
      float S = wavepart[0][tid][0] + wavepart[1][tid][0] + wavepart[2][tid][0] + wavepart[3][tid][0];
      float Q = wavepart[0][tid][1] + wavepart[1][tid][1] + wavepart[2][tid][1] + wavepart[3][tid][1];
      u64 w = ((u64)__float_as_uint(Q) << 32) | (u64)__float_as_uint(S);
      st_u64(zbuf + (fb + wid)*BPC + tid, w);
    }
    asm volatile("s_waitcnt vmcnt(0)" ::: "memory");   // wave-level drain of zbuf stores
    __syncthreads();                                   // all waves drained
    if (tid == 0) st_tag(zflag + fb + wid, 0.0f, tag); // flag AFTER payload@LLC
    if (tid < 8 && (gate*8 + tid) != wid){
      const u64* fp = zflag + fb + gate*8 + tid;
      while ((unsigned)(ld_u64(fp) >> 32) != tag) { }
    }
    __syncthreads();

    // ---- phase 2: read peer z-stats (8 peers), LN(z)+act, publish acts ----
    if (bvalid){
      float Ssum[4], Qsum[4];
      #pragma unroll
      for (int r=0;r<4;r++){ Ssum[r]=0.f; Qsum[r]=0.f; }
      #pragma unroll
      for (int jh=0; jh<2; jh++){
        u64 zw[4][4];
        #pragma unroll
        for (int jj=0;jj<4;jj++)
          #pragma unroll
          for (int r=0;r<4;r++)
            zw[jj][r] = ld_u64(zbuf + (fb + gate*8 + jh*4 + jj)*BPC + b_base + r);
        #pragma unroll
        for (int jj=0;jj<4;jj++)
          #pragma unroll
          for (int r=0;r<4;r++){ Ssum[r] += lo_f(zw[jj][r]); Qsum[r] += hi_f(zw[jj][r]); }
      }
      #pragma unroll
      for (int r=0;r<4;r++){
        float m_ = Ssum[r] * (1.0f/512.0f);
        float var = Qsum[r] * (1.0f/512.0f) - m_*m_;
        float rstd = rsqrtf(var + 1e-3f);
        float zn = (z[r] - m_) * rstd * gam_r + bet_r;
        float a = (gate==1) ? tanh_fast(zn) : sigf(zn);
        st_f32(actf + (size_t)((par*NC + cid)*BPC + b_base + r)*NU + ng, a);
      }
    }
    asm volatile("s_waitcnt vmcnt(0)" ::: "memory");   // drain act stores (per wave)
    __syncthreads();                                   // all waves drained
    if (tid == 0) st_tag(aflag + fb + wid, 0.0f, tag);
    if (tid < 32 && tid != wid){
      const u64* fp = aflag + fb + tid;
      while ((unsigned)(ld_u64(fp) >> 32) != tag) { }
    }
    __syncthreads();

    // ---- phase 3: coalesced value-only act read, replicated c/h update ----
    {
      const float* abf = actf + (size_t)((par*NC + cid)*BPC + b_loc)*NU;
      float cn[16], og[16];
      float ls = 0.f, lq = 0.f;
      #pragma unroll
      for (int ch=0; ch<2; ch++){
        u64 w[4][4];
        #pragma unroll
        for (int g=0; g<4; g++)
          #pragma unroll
          for (int jj=0; jj<4; jj++)
            w[g][jj] = ld_u64((const u64*)(abf + (size_t)g*512 + (ch*4+jj)*64 + l2));
        #pragma unroll
        for (int jj=0; jj<4; jj++)
          #pragma unroll
          for (int e=0; e<2; e++){
            int k = ch*8 + jj*2 + e;
            float fv = e ? hi_f(w[0][jj]) : lo_f(w[0][jj]);
            float gv = e ? hi_f(w[1][jj]) : lo_f(w[1][jj]);
            float iv = e ? hi_f(w[2][jj]) : lo_f(w[2][jj]);
            float ov = e ? hi_f(w[3][jj]) : lo_f(w[3][jj]);
            float cv = c[k]*fv + gv*iv;
            cn[k] = cv;
            og[k] = ov;
            ls += cv; lq += cv*cv;
          }
      }
      #pragma unroll
      for (int off=1; off<32; off<<=1){ ls += __shfl_xor(ls, off); lq += __shfl_xor(lq, off); }
      float m_ = ls*(1.0f/512.0f);
      float var = lq*(1.0f/512.0f) - m_*m_;
      float rs = rsqrtf(var + 1e-3f);
      #pragma unroll
      for (int j=0; j<8; j++){
        int u0 = j*64 + l2;
        float cl0 = (cn[2*j+0]-m_)*rs*gamma_lds[GIDX(u0)]   + beta_lds[GIDX(u0)];
        float cl1 = (cn[2*j+1]-m_)*rs*gamma_lds[GIDX(u0+1)] + beta_lds[GIDX(u0+1)];
        c[2*j+0] = cl0; c[2*j+1] = cl1;
        float hv0 = og[2*j+0]*tanh_fast(cl0);
        float hv1 = og[2*j+1]*tanh_fast(cl1);
        ushort2 hh; hh.x = f2bf(hv0); hh.y = f2bf(hv1);
        ushort2 hl; hl.x = f2bf(hv0 - bf2f(hh.x)); hl.y = f2bf(hv1 - bf2f(hh.y));
        *(ushort2*)&h_hi[b_loc][u0] = hh;
        *(ushort2*)&h_lo[b_loc][u0] = hl;
        if (wid == 0){
          float2 hv; hv.x = hv0; hv.y = hv1;
          *(float2*)&out[((size_t)(cid*BPC + b_loc)*Tn + t)*Un + u0] = hv;
        }
      }
    }
    __syncthreads();   // h_lds ready for next step's MFMA
  }
}

extern "C" void kernel_launch(void* const* d_in, const int* in_sizes, int n_in,
                              void* d_out, int out_size, void* d_ws, size_t ws_size,
                              hipStream_t stream){
  const float* x     = (const float*)d_in[0];
  const float* h0    = (const float*)d_in[1];
  const float* c0    = (const float*)d_in[2];
  const float* Wf    = (const float*)d_in[3];
  const float* bf_   = (const float*)d_in[4];
  const float* Wg    = (const float*)d_in[5];
  const float* bg_   = (const float*)d_in[6];
  const float* Wi    = (const float*)d_in[7];
  const float* bi_   = (const float*)d_in[8];
  const float* Wo    = (const float*)d_in[9];
  const float* bo_   = (const float*)d_in[10];
  const float* gamma = (const float*)d_in[11];
  const float* beta  = (const float*)d_in[12];

  char* ws = (char*)d_ws;
  __half*   xz    = (__half*)(ws);                             // 256 MiB
  ushort_t* wh_hi = (ushort_t*)(ws + (256ull<<20));            // 2 MiB
  ushort_t* wh_lo = (ushort_t*)(ws + (258ull<<20));            // 2 MiB
  float*    actf  = (float*)(ws + (260ull<<20));               // 2 MiB (f32 acts, 2 par x 16 cid x 8 b)
  u64*      zbuf  = (u64*)(ws + (262ull<<20));                 // 64 KiB (packed S,Q; 1024 x 8 x 8B)
  u64*      zflag = (u64*)(ws + (262ull<<20) + (64ull<<10));   // 8 KiB (1024 flags)
  u64*      aflag = (u64*)(ws + (262ull<<20) + (72ull<<10));   // 8 KiB
  float* out = (float*)d_out;

  // clear flags only (tag 0 never equals t+1): zflag + aflag = 16 KiB contiguous
  hipMemsetAsync(zflag, 0, 16ull<<10, stream);
  k_prep_w<<<4096, 256, 0, stream>>>(Wf, Wg, Wi, Wo, wh_hi, wh_lo);
  dim3 g(Bsz*Tn/128, NU/128);
  k_gemm_xz<<<g, 256, 0, stream>>>(x, Wf, Wg, Wi, Wo, xz);
  k_lstm<<<512, 256, 0, stream>>>(wh_hi, wh_lo, xz, bf_, bg_, bi_, bo_, gamma, beta, h0, c0,
                                  actf, zbuf, zflag, aflag, out);
}

// Round 6
// 6355.944 us; speedup vs baseline: 1.2032x; 1.2032x over previous
//
#include <hip/hip_runtime.h>
#include <hip/hip_fp16.h>

// LayerNormLSTMCell: B=128, T=512, D=512, U=512, 4 gates (f,g,i,o), shared LN.
// Numerics: split-bf16 (hi+lo) on both operands of every GEMM, 3-product MFMA
// (hi*hi + lo*hi + hi*lo) ~= fp32; xz stored fp16. PASSED r3 at absmax 0.0039.
//
// Exchange protocol (R8/R9, verified): value-only payload via relaxed
// agent-scope stores (write-through LLC), ordered by one tagged FLAG per
// producer WG: payload -> s_waitcnt vmcnt(0) -> __syncthreads -> flag;
// consumer: 1 thread/producer spins flag -> __syncthreads -> coalesced loads.
// Parity double-buffer overwrite safety: producer's t+2 write ordered after
// every consumer's t read via the all-flags gate.
//
// R10 lesson (reverted): 2 WG/CU caps the unified VGPR+AGPR file at 256/lane;
// weights (256 regs/lane at WPC=16) no longer fit -> compiler rematerialized
// weight loads every step -> FETCH 419MB->2.3GB, dur +30%. Register-resident
// weights REQUIRE 1 WG/CU. (16 clusters x 4MB = 64MB = half the chip's regs.)
//
// R11: hop elimination. R9 spent ~9us/step on TWO sequential cluster-wide LLC
// rounds (z-stats, then acts) -- each ~4.5us incl. drain+spin+skew, vs ~1.5us
// compute. Raw z is the SAME exchange volume as acts (2048 f32/batch). So:
// publish z once; each batch-owner group reads full z[b][2048], computes
// LN-stats (shfl reduce) + activations + c-update + LN(c) + h LOCALLY
// (8x redundant VALU in-cluster, ~0.75us -- cheap vs a hop). Deletes the
// z-stat exchange, phase 2, wavepart, and 3 barriers: ONE hop per step.

typedef unsigned short ushort_t;
typedef unsigned long long u64;
typedef __attribute__((ext_vector_type(8))) short short8;
typedef __attribute__((ext_vector_type(4))) float f32x4;

#define Bsz 128
#define Tn  512
#define Un  512
#define NU  2048
#define NC  16     // clusters
#define WPC 16     // WGs per cluster (each owns 128 units of one gate)
#define BPC 8      // batches per cluster

#define GIDX(u) ((u) + ((u) >> 5))   // LDS skew for gamma/beta

__device__ __forceinline__ ushort_t f2bf(float f){
  unsigned u = __float_as_uint(f);
  u = u + 0x7fffu + ((u >> 16) & 1u);   // RNE
  return (ushort_t)(u >> 16);
}
__device__ __forceinline__ float bf2f(ushort_t h){
  return __uint_as_float(((unsigned)h) << 16);
}
__device__ __forceinline__ float sigf(float x){ return 1.0f/(1.0f + __expf(-x)); }
__device__ __forceinline__ float tanh_fast(float x){
  float ax = fabsf(x);
  float e  = __expf(-2.0f*ax);          // in (0,1], no overflow
  float r  = (1.0f - e)/(1.0f + e);
  return x >= 0.0f ? r : -r;
}

// ---- LLC-direct primitives (relaxed agent scope) ----
__device__ __forceinline__ void st_tag(u64* p, float v, unsigned tag){
  u64 w = ((u64)tag << 32) | (u64)__float_as_uint(v);
  __hip_atomic_store(p, w, __ATOMIC_RELAXED, __HIP_MEMORY_SCOPE_AGENT);
}
__device__ __forceinline__ void st_f32(float* p, float v){
  __hip_atomic_store(p, v, __ATOMIC_RELAXED, __HIP_MEMORY_SCOPE_AGENT);
}
__device__ __forceinline__ u64 ld_u64(const u64* p){
  return __hip_atomic_load(p, __ATOMIC_RELAXED, __HIP_MEMORY_SCOPE_AGENT);
}
__device__ __forceinline__ float lo_f(u64 w){ return __uint_as_float((unsigned)w); }
__device__ __forceinline__ float hi_f(u64 w){ return __uint_as_float((unsigned)(w >> 32)); }

// ---------------- weight prep: Wh -> fragment-ordered hi/lo ----------------
__global__ void k_prep_w(const float* __restrict__ Wf, const float* __restrict__ Wg,
                         const float* __restrict__ Wi, const float* __restrict__ Wo,
                         ushort_t* __restrict__ wh_hi, ushort_t* __restrict__ wh_lo){
  int idx = blockIdx.x*blockDim.x + threadIdx.x;
  if (idx >= 1048576) return;
  const float* Wp[4] = {Wf, Wg, Wi, Wo};
  int j = idx & 7;
  int lane = (idx >> 3) & 63;
  int i = (idx >> 9) & 31;
  int wslot = idx >> 14;
  int kiter = i >> 1, nt = i & 1;
  int wid = wslot >> 2, wave = wslot & 3;
  int n = wid*128 + wave*32 + nt*16 + (lane & 15);
  int k = kiter*32 + (lane >> 4)*8 + j;
  int gate = n >> 9, u = n & 511;
  float w = Wp[gate][u*1024 + k];
  ushort_t hi = f2bf(w);
  wh_hi[idx] = hi;
  wh_lo[idx] = f2bf(w - bf2f(hi));
}

// ---------------- xz = x @ Wx^T  (split-bf16 MFMA, 128x128 tile, BK=32) ----------------
__global__ __launch_bounds__(256,2) void k_gemm_xz(const float* __restrict__ A,
    const float* __restrict__ Wf, const float* __restrict__ Wg,
    const float* __restrict__ Wi, const float* __restrict__ Wo,
    __half* __restrict__ C){
  __shared__ __align__(16) ushort_t Ah[128*32];
  __shared__ __align__(16) ushort_t Al[128*32];
  __shared__ __align__(16) ushort_t Bh[128*32];
  __shared__ __align__(16) ushort_t Bl[128*32];
  const int tid  = threadIdx.x;
  const int lane = tid & 63, wave = tid >> 6;
  const int quad = lane >> 4, l15 = lane & 15;
  const int wm = wave >> 1, wn = wave & 1;
  const int m0 = blockIdx.x * 128, n0 = blockIdx.y * 128;
  const float* Wp = (n0 < 512) ? Wf : (n0 < 1024) ? Wg : (n0 < 1536) ? Wi : Wo;
  const int u0 = n0 & 511;
  f32x4 acc[4][4];
  #pragma unroll
  for (int a=0;a<4;a++)
    #pragma unroll
    for (int b=0;b<4;b++) acc[a][b] = (f32x4){0.f,0.f,0.f,0.f};

  for (int kc = 0; kc < 512; kc += 32){
    __syncthreads();
    #pragma unroll
    for (int p=0; p<4; p++){
      int slot = p*256 + tid;
      int row = slot >> 3, seg = slot & 7;
      float4 va = *(const float4*)(A  + (size_t)(m0+row)*512  + kc + seg*4);
      float4 vb = *(const float4*)(Wp + (size_t)(u0+row)*1024 + 512 + kc + seg*4);
      ushort4 ah, al, bh, bl;
      ah.x=f2bf(va.x); al.x=f2bf(va.x-bf2f(ah.x));
      ah.y=f2bf(va.y); al.y=f2bf(va.y-bf2f(ah.y));
      ah.z=f2bf(va.z); al.z=f2bf(va.z-bf2f(ah.z));
      ah.w=f2bf(va.w); al.w=f2bf(va.w-bf2f(ah.w));
      bh.x=f2bf(vb.x); bl.x=f2bf(vb.x-bf2f(bh.x));
      bh.y=f2bf(vb.y); bl.y=f2bf(vb.y-bf2f(bh.y));
      bh.z=f2bf(vb.z); bl.z=f2bf(vb.z-bf2f(bh.z));
      bh.w=f2bf(vb.w); bl.w=f2bf(vb.w-bf2f(bh.w));
      *(ushort4*)(Ah + slot*4) = ah;
      *(ushort4*)(Al + slot*4) = al;
      *(ushort4*)(Bh + slot*4) = bh;
      *(ushort4*)(Bl + slot*4) = bl;
    }
    __syncthreads();
    short8 afh[4], afl[4], bfh[4], bfl[4];
    #pragma unroll
    for (int ti=0; ti<4; ti++){
      afh[ti] = *(const short8*)(Ah + (wm*64 + ti*16 + l15)*32 + quad*8);
      afl[ti] = *(const short8*)(Al + (wm*64 + ti*16 + l15)*32 + quad*8);
    }
    #pragma unroll
    for (int tj=0; tj<4; tj++){
      bfh[tj] = *(const short8*)(Bh + (wn*64 + tj*16 + l15)*32 + quad*8);
      bfl[tj] = *(const short8*)(Bl + (wn*64 + tj*16 + l15)*32 + quad*8);
    }
    #pragma unroll
    for (int ti=0; ti<4; ti++)
      #pragma unroll
      for (int tj=0; tj<4; tj++){
        acc[ti][tj] = __builtin_amdgcn_mfma_f32_16x16x32_bf16(afh[ti], bfh[tj], acc[ti][tj], 0,0,0);
        acc[ti][tj] = __builtin_amdgcn_mfma_f32_16x16x32_bf16(afl[ti], bfh[tj], acc[ti][tj], 0,0,0);
        acc[ti][tj] = __builtin_amdgcn_mfma_f32_16x16x32_bf16(afh[ti], bfl[tj], acc[ti][tj], 0,0,0);
      }
  }
  #pragma unroll
  for (int ti=0; ti<4; ti++)
    #pragma unroll
    for (int tj=0; tj<4; tj++)
      #pragma unroll
      for (int r=0; r<4; r++){
        int m = m0 + wm*64 + ti*16 + quad*4 + r;
        int n = n0 + wn*64 + tj*16 + l15;
        C[(size_t)m*NU + n] = __float2half(acc[ti][tj][r]);
      }
}

// ---------------- persistent LSTM ----------------
__global__ __launch_bounds__(256,1) void k_lstm(
    const ushort_t* __restrict__ wh_hi_g, const ushort_t* __restrict__ wh_lo_g,
    const __half* __restrict__ xz,
    const float* __restrict__ bfp, const float* __restrict__ bgp,
    const float* __restrict__ bip, const float* __restrict__ bop,
    const float* __restrict__ gamma, const float* __restrict__ beta,
    const float* __restrict__ h0, const float* __restrict__ c0,
    float* __restrict__ zex, u64* __restrict__ zflag,
    float* __restrict__ out)
{
  const int bid = blockIdx.x;
  const int cid = bid & 15;          // cluster
  const int wid = bid >> 4;          // 0..15; owns units [wid*128, wid*128+128)
  const int tid = threadIdx.x;
  const int wave = tid >> 6, lane = tid & 63;
  const int quad = lane >> 4, l15 = lane & 15;
  const int gate = wid >> 2;

  __shared__ __align__(16) ushort_t h_hi[16][520];   // rows 8..15 stay zero (M=8 pad to 16)
  __shared__ __align__(16) ushort_t h_lo[16][520];
  __shared__ float gamma_lds[528], beta_lds[528];    // skew-indexed via GIDX

  for (int i = tid; i < 16*520; i += 256){
    int r = i / 520, u = i - r*520;
    float v = (r < BPC && u < 512) ? h0[(cid*BPC + r)*512 + u] : 0.0f;
    ushort_t hh = f2bf(v);
    h_hi[r][u] = hh;
    h_lo[r][u] = f2bf(v - bf2f(hh));
  }
  for (int i = tid; i < 512; i += 256){ gamma_lds[GIDX(i)] = gamma[i]; beta_lds[GIDX(i)] = beta[i]; }

  // replicated c-state: thread owns (b_loc, 16 units interleaved)
  // unit(k) = (k>>1)*64 + (tid&31)*2 + (k&1)
  const int b_loc = tid >> 5;
  const int l2 = (tid & 31) << 1;
  float c[16];
  #pragma unroll
  for (int i=0;i<16;i++) c[i] = c0[(cid*BPC + b_loc)*512 + (i>>1)*64 + l2 + (i&1)];

  // VGPR/AGPR-resident Wh B-fragments, hi+lo (requires 1 WG/CU: 512-reg file)
  short8 wrh[32], wrl[32];
  {
    const ushort_t* wph = wh_hi_g + (size_t)(wid*4 + wave)*16384 + lane*8;
    const ushort_t* wpl = wh_lo_g + (size_t)(wid*4 + wave)*16384 + lane*8;
    #pragma unroll
    for (int i=0;i<32;i++){
      wrh[i] = *(const short8*)(wph + (size_t)i*512);
      wrl[i] = *(const short8*)(wpl + (size_t)i*512);
    }
  }

  float bias_r[2];
  int ng_[2];
  #pragma unroll
  for (int nt=0; nt<2; nt++){
    int ng = wid*128 + wave*32 + nt*16 + l15;
    ng_[nt] = ng;
    int u = ng & 511;
    const float* bp = (gate==0)? bfp : (gate==1)? bgp : (gate==2)? bip : bop;
    bias_r[nt] = bp[u];
  }
  const bool bvalid = (quad < 2);
  const int b_base = quad*4;

  __syncthreads();

  for (int t = 0; t < Tn; ++t){
    const unsigned tag = (unsigned)(t + 1);
    const int par = t & 1;
    const size_t fb = (size_t)(par*NC + cid)*WPC;
    // ---- phase 1: z = h @ Wh^T + xz + bias  (split-bf16, 3 products) ----
    float xzv[2][4];
    #pragma unroll
    for (int nt=0; nt<2; nt++)
      #pragma unroll
      for (int r=0; r<4; r++){
        if (bvalid){
          int b = cid*BPC + b_base + r;
          xzv[nt][r] = __half2float(xz[((size_t)b*Tn + t)*NU + ng_[nt]]);
        } else xzv[nt][r] = 0.0f;
      }
    f32x4 acc0 = (f32x4){0.f,0.f,0.f,0.f}, acc1 = (f32x4){0.f,0.f,0.f,0.f};
    #pragma unroll
    for (int ki=0; ki<16; ki++){
      short8 afh = *(const short8*)(&h_hi[l15][ki*32 + quad*8]);
      short8 afl = *(const short8*)(&h_lo[l15][ki*32 + quad*8]);
      acc0 = __builtin_amdgcn_mfma_f32_16x16x32_bf16(afh, wrh[2*ki+0], acc0, 0,0,0);
      acc0 = __builtin_amdgcn_mfma_f32_16x16x32_bf16(afl, wrh[2*ki+0], acc0, 0,0,0);
      acc0 = __builtin_amdgcn_mfma_f32_16x16x32_bf16(afh, wrl[2*ki+0], acc0, 0,0,0);
      acc1 = __builtin_amdgcn_mfma_f32_16x16x32_bf16(afh, wrh[2*ki+1], acc1, 0,0,0);
      acc1 = __builtin_amdgcn_mfma_f32_16x16x32_bf16(afl, wrh[2*ki+1], acc1, 0,0,0);
      acc1 = __builtin_amdgcn_mfma_f32_16x16x32_bf16(afh, wrl[2*ki+1], acc1, 0,0,0);
    }
    // publish raw z (value-only) for own units x own 4 batches
    if (bvalid){
      #pragma unroll
      for (int r=0;r<4;r++){
        float z0 = acc0[r] + xzv[0][r] + bias_r[0];
        float z1 = acc1[r] + xzv[1][r] + bias_r[1];
        float* zp = zex + (size_t)((par*NC + cid)*BPC + b_base + r)*NU;
        st_f32(zp + ng_[0], z0);
        st_f32(zp + ng_[1], z1);
      }
    }
    asm volatile("s_waitcnt vmcnt(0)" ::: "memory");   // wave-level drain of z stores
    __syncthreads();                                   // all waves drained
    if (tid == 0) st_tag(zflag + fb + wid, 0.0f, tag); // flag AFTER payload@LLC
    if (tid < WPC && tid != wid){
      const u64* fp = zflag + fb + tid;
      while ((unsigned)(ld_u64(fp) >> 32) != tag) { }
    }
    __syncthreads();

    // ---- phase 2: read full z for own batch, LOCAL stats+LN+act+c/h ----
    {
      const float* zbf = zex + (size_t)((par*NC + cid)*BPC + b_loc)*NU;
      u64 zv[2][4][4];   // [ch][gate][jj]
      #pragma unroll
      for (int ch=0; ch<2; ch++)
        #pragma unroll
        for (int g=0; g<4; g++)
          #pragma unroll
          for (int jj=0; jj<4; jj++)
            zv[ch][g][jj] = ld_u64((const u64*)(zbf + (size_t)g*512 + (ch*4+jj)*64 + l2));
      // per-gate LN stats over 512 units (32 lanes x 16 vals each)
      float mg[4], rg[4];
      #pragma unroll
      for (int g=0; g<4; g++){
        float s=0.f, q=0.f;
        #pragma unroll
        for (int ch=0; ch<2; ch++)
          #pragma unroll
          for (int jj=0; jj<4; jj++){
            float a = lo_f(zv[ch][g][jj]), b = hi_f(zv[ch][g][jj]);
            s += a + b; q += a*a + b*b;
          }
        #pragma unroll
        for (int off=1; off<32; off<<=1){ s += __shfl_xor(s, off); q += __shfl_xor(q, off); }
        float m_ = s*(1.0f/512.0f);
        float v_ = q*(1.0f/512.0f) - m_*m_;
        mg[g] = m_; rg[g] = rsqrtf(v_ + 1e-3f);
      }
      float cn[16], og[16];
      float ls = 0.f, lq = 0.f;
      #pragma unroll
      for (int ch=0; ch<2; ch++)
        #pragma unroll
        for (int jj=0; jj<4; jj++)
          #pragma unroll
          for (int e=0; e<2; e++){
            int k = ch*8 + jj*2 + e;
            int u0 = (ch*4+jj)*64 + l2 + e;
            float gam = gamma_lds[GIDX(u0)], bet = beta_lds[GIDX(u0)];
            float zf = e ? hi_f(zv[ch][0][jj]) : lo_f(zv[ch][0][jj]);
            float zg = e ? hi_f(zv[ch][1][jj]) : lo_f(zv[ch][1][jj]);
            float zi = e ? hi_f(zv[ch][2][jj]) : lo_f(zv[ch][2][jj]);
            float zo = e ? hi_f(zv[ch][3][jj]) : lo_f(zv[ch][3][jj]);
            float fv = sigf     ((zf - mg[0])*rg[0]*gam + bet);
            float gv = tanh_fast((zg - mg[1])*rg[1]*gam + bet);
            float iv = sigf     ((zi - mg[2])*rg[2]*gam + bet);
            float ov = sigf     ((zo - mg[3])*rg[3]*gam + bet);
            float cv = c[k]*fv + gv*iv;
            cn[k] = cv; og[k] = ov;
            ls += cv; lq += cv*cv;
          }
      #pragma unroll
      for (int off=1; off<32; off<<=1){ ls += __shfl_xor(ls, off); lq += __shfl_xor(lq, off); }
      float m_ = ls*(1.0f/512.0f);
      float var = lq*(1.0f/512.0f) - m_*m_;
      float rs = rsqrtf(var + 1e-3f);
      #pragma unroll
      for (int j=0; j<8; j++){
        int u0 = j*64 + l2;
        float cl0 = (cn[2*j+0]-m_)*rs*gamma_lds[GIDX(u0)]   + beta_lds[GIDX(u0)];
        float cl1 = (cn[2*j+1]-m_)*rs*gamma_lds[GIDX(u0+1)] + beta_lds[GIDX(u0+1)];
        c[2*j+0] = cl0; c[2*j+1] = cl1;
        float hv0 = og[2*j+0]*tanh_fast(cl0);
        float hv1 = og[2*j+1]*tanh_fast(cl1);
        ushort2 hh; hh.x = f2bf(hv0); hh.y = f2bf(hv1);
        ushort2 hl; hl.x = f2bf(hv0 - bf2f(hh.x)); hl.y = f2bf(hv1 - bf2f(hh.y));
        *(ushort2*)&h_hi[b_loc][u0] = hh;
        *(ushort2*)&h_lo[b_loc][u0] = hl;
        if (wid == 0){
          float2 hv; hv.x = hv0; hv.y = hv1;
          *(float2*)&out[((size_t)(cid*BPC + b_loc)*Tn + t)*Un + u0] = hv;
        }
      }
    }
    __syncthreads();   // h_lds ready for next step's MFMA
  }
}

extern "C" void kernel_launch(void* const* d_in, const int* in_sizes, int n_in,
                              void* d_out, int out_size, void* d_ws, size_t ws_size,
                              hipStream_t stream){
  const float* x     = (const float*)d_in[0];
  const float* h0    = (const float*)d_in[1];
  const float* c0    = (const float*)d_in[2];
  const float* Wf    = (const float*)d_in[3];
  const float* bf_   = (const float*)d_in[4];
  const float* Wg    = (const float*)d_in[5];
  const float* bg_   = (const float*)d_in[6];
  const float* Wi    = (const float*)d_in[7];
  const float* bi_   = (const float*)d_in[8];
  const float* Wo    = (const float*)d_in[9];
  const float* bo_   = (const float*)d_in[10];
  const float* gamma = (const float*)d_in[11];
  const float* beta  = (const float*)d_in[12];

  char* ws = (char*)d_ws;
  __half*   xz    = (__half*)(ws);                             // 256 MiB
  ushort_t* wh_hi = (ushort_t*)(ws + (256ull<<20));            // 2 MiB
  ushort_t* wh_lo = (ushort_t*)(ws + (258ull<<20));            // 2 MiB
  float*    zex   = (float*)(ws + (260ull<<20));               // 2 MiB (raw z, 2 par x 16 cid x 8 b x 2048)
  u64*      zflag = (u64*)(ws + (262ull<<20));                 // 4 KiB (2 x 16 x 16 flags)
  float* out = (float*)d_out;

  // clear flags only (tag 0 never equals t+1)
  hipMemsetAsync(zflag, 0, 4ull<<10, stream);
  k_prep_w<<<4096, 256, 0, stream>>>(Wf, Wg, Wi, Wo, wh_hi, wh_lo);
  dim3 g(Bsz*Tn/128, NU/128);
  k_gemm_xz<<<g, 256, 0, stream>>>(x, Wf, Wg, Wi, Wo, xz);
  k_lstm<<<256, 256, 0, stream>>>(wh_hi, wh_lo, xz, bf_, bg_, bi_, bo_, gamma, beta, h0, c0,
                                  zex, zflag, out);
}